// Round 14
// baseline (61.972 us; speedup 1.0000x reference)
//
#include <hip/hip_runtime.h>

typedef _Float16 half8 __attribute__((ext_vector_type(8)));
typedef _Float16 half4 __attribute__((ext_vector_type(4)));
typedef float f32x4 __attribute__((ext_vector_type(4)));

#define W 512
#define H 512
#define NPIX (16.0f*3.0f*512.0f*512.0f)
#define NACC 64
#define TPSTR 80           // TP rowidx capacity per outcol (halves)
#define TPL 2560           // halves per TP plane = 32*TPSTR

#define MFMA(A,B) __builtin_amdgcn_mfma_f32_16x16x32_f16((A),(B),zero4,0,0,0)

// Block = 64 out rows x 32 out cols, 256 threads (4 waves).
// LDS = TP only (~20.6 KB) -> 7 blocks/CU cap: cross-block latency hiding.
// Grid = 48 planes x 8 ty x 16 tx = 6144 one-shot blocks.
__global__ __launch_bounds__(256) void ssim_main(const float* __restrict__ pred,
                                                 const float* __restrict__ targ,
                                                 const float* __restrict__ win,
                                                 float* __restrict__ acc) {
    const int tid  = threadIdx.x;
    const int lane = tid & 63;
    const int wv   = tid >> 6;          // wave 0..3
    const int lo   = lane & 15;
    const int hi   = lane >> 4;

    __shared__ _Float16 TP[4 * TPL];    // 20480 B: 0:mu1 1:mu2 2:q 3:pt
    __shared__ _Float16 gw[64];
    __shared__ float wsum[4];

    // gw[18+d] = g[d] for d in [0,10], zero elsewhere (g from window row 5).
    if (tid < 64) {
        const int d = tid - 18;
        float val = 0.f;
        if (d >= 0 && d <= 10)
            val = win[55 + d] * __builtin_amdgcn_rcpf(sqrtf(win[60]));
        gw[tid] = (_Float16)val;
    }
    __syncthreads();

    // Band matrix (both passes): B[n][k] = g[k - n - 3]  (validated R6-R13).
    half8 Bw;
    #pragma unroll
    for (int j = 0; j < 8; ++j)
        Bw[j] = gw[15 + hi * 8 + j - lo];

    // Tile coords with XCD swizzle (6144 % 8 == 0, bijective).
    const int b  = (blockIdx.x & 7) * 768 + (blockIdx.x >> 3);
    const int nc = b >> 7, rem = b & 127;
    const int y0 = (rem >> 4) * 64, x0 = (rem & 15) * 32;
    const float* Pb = pred + (size_t)nc * (W * H);
    const float* Tb = targ + (size_t)nc * (W * H);

    const f32x4 zero4 = {0.f, 0.f, 0.f, 0.f};
    const float C1 = 1e-4f, C2 = 9e-4f;

    // ---- H-pass: 10 tasks (rt 0..4 x ct 0..1) over 4 waves, direct global
    // loads (no stage). A row m = lo -> global y = y0-8+16rt+lo;
    // k = 16ct+hi*8+j -> global x = x0-8+16ct+hi*8+j.
    // TP rowidx 77..79 get finite junk whose band weight is exactly 0.
    #pragma unroll
    for (int it = 0; it < 3; ++it) {
        const int t = wv + it * 4;
        if (t < 10) {                              // wave-uniform
            const int rt = t >> 1, ct = t & 1;
            const int rowbase = y0 - 8 + rt * 16;
            const int cb0     = x0 - 8 + ct * 16;
            const int row     = rowbase + lo;
            const int cbase   = cb0 + hi * 8;
            float pf[8], tf[8];
            if (rowbase >= 0 && rowbase + 15 < H && cb0 >= 0 && cb0 + 31 < W) {
                const float* Pp = Pb + (size_t)row * W + cbase;
                const float* Tp = Tb + (size_t)row * W + cbase;
                *(f32x4*)&pf[0] = *(const f32x4*)Pp;
                *(f32x4*)&pf[4] = *(const f32x4*)(Pp + 4);
                *(f32x4*)&tf[0] = *(const f32x4*)Tp;
                *(f32x4*)&tf[4] = *(const f32x4*)(Tp + 4);
            } else {
                const bool rok = (unsigned)row < H;
                const int  rid = rok ? row : 0;
                #pragma unroll
                for (int j = 0; j < 8; ++j) {
                    const int  c  = cbase + j;
                    const int  ci = ((unsigned)c < W) ? c : 0;
                    const bool ok = rok && ((unsigned)c < W);
                    const float pv = Pb[(size_t)rid * W + ci];
                    const float tv = Tb[(size_t)rid * W + ci];
                    pf[j] = ok ? pv : 0.f;         // zero padding
                    tf[j] = ok ? tv : 0.f;
                }
            }
            half8 pa, ta;
            #pragma unroll
            for (int j = 0; j < 8; ++j) {
                pa[j] = (_Float16)pf[j];
                ta[j] = (_Float16)tf[j];
            }
            const half8 qa = pa * pa + ta * ta;    // q = p^2 + t^2 (fp16, as R13)
            const half8 xa = pa * ta;              // x = p*t
            const f32x4 d0 = MFMA(pa, Bw);
            const f32x4 d1 = MFMA(ta, Bw);
            const f32x4 d2 = MFMA(qa, Bw);
            const f32x4 d3 = MFMA(xa, Bw);
            const int tb = (ct * 16 + lo) * TPSTR + rt * 16 + hi * 4;
            half4 h0, h1, h2, h3;
            #pragma unroll
            for (int r = 0; r < 4; ++r) {
                h0[r] = (_Float16)d0[r]; h1[r] = (_Float16)d1[r];
                h2[r] = (_Float16)d2[r]; h3[r] = (_Float16)d3[r];
            }
            *(half4*)&TP[0 * TPL + tb] = h0;
            *(half4*)&TP[1 * TPL + tb] = h1;
            *(half4*)&TP[2 * TPL + tb] = h2;
            *(half4*)&TP[3 * TPL + tb] = h3;
        }
    }
    __syncthreads();

    // ---- V-pass + SSIM epilogue: 8 tasks (rtv 0..3 x ct 0..1), 2/wave. ----
    float sum = 0.f;
    #pragma unroll
    for (int iv = 0; iv < 2; ++iv) {
        const int v = wv + iv * 4;
        const int rtv = v >> 1, ct = v & 1;
        const int ah = (ct * 16 + lo) * TPSTR + rtv * 16 + hi * 8;
        const half8 a0 = *(const half8*)&TP[0 * TPL + ah];
        const half8 a1 = *(const half8*)&TP[1 * TPL + ah];
        const half8 a2 = *(const half8*)&TP[2 * TPL + ah];
        const half8 a3 = *(const half8*)&TP[3 * TPL + ah];
        const f32x4 m1 = MFMA(a0, Bw);
        const f32x4 m2 = MFMA(a1, Bw);
        const f32x4 qq = MFMA(a2, Bw);
        const f32x4 pt = MFMA(a3, Bw);
        #pragma unroll
        for (int r = 0; r < 4; ++r) {
            const float mu1 = m1[r], mu2 = m2[r];
            const float ms  = fmaf(mu1, mu1, mu2 * mu2);   // mu1^2 + mu2^2
            const float m12 = mu1 * mu2;
            const float s12 = pt[r] - m12;                 // sigma12
            const float ssm = qq[r] - ms;                  // sigma1^2 + sigma2^2
            const float num = fmaf(2.f, m12, C1) * fmaf(2.f, s12, C2);
            const float den = (ms + C1) * (ssm + C2);
            sum += num * __builtin_amdgcn_rcpf(den);
        }
    }

    // ---- Reduce: wave -> block -> one atomic per block (64 slots). ----
    #pragma unroll
    for (int off = 32; off > 0; off >>= 1) sum += __shfl_down(sum, off, 64);
    if (lane == 0) wsum[wv] = sum;
    __syncthreads();
    if (tid == 0)
        atomicAdd(&acc[blockIdx.x & (NACC - 1)], wsum[0] + wsum[1] + wsum[2] + wsum[3]);
}

__global__ void ssim_final(const float* __restrict__ acc, float* __restrict__ out) {
    float s = 0.f;
    #pragma unroll
    for (int i = 0; i < NACC; ++i) s += acc[i];
    out[0] = 0.1f * (1.0f - s / NPIX);
}

extern "C" void kernel_launch(void* const* d_in, const int* in_sizes, int n_in,
                              void* d_out, int out_size, void* d_ws, size_t ws_size,
                              hipStream_t stream) {
    const float* pred = (const float*)d_in[0];
    const float* targ = (const float*)d_in[1];
    const float* win  = (const float*)d_in[2];
    float* out = (float*)d_out;
    float* acc = (float*)d_ws;

    hipMemsetAsync(acc, 0, NACC * sizeof(float), stream);  // fresh accumulators
    ssim_main<<<6144, 256, 0, stream>>>(pred, targ, win, acc);
    ssim_final<<<1, 1, 0, stream>>>(acc, out);
}